// Round 22
// baseline (164.177 us; speedup 1.0000x reference)
//
#include <hip/hip_runtime.h>
#include <math.h>

#define B_    4
#define N_    4096
#define C_    512
#define KSLOT 683

using bf16x8 = __attribute__((ext_vector_type(8))) short;
using f32x4  = __attribute__((ext_vector_type(4))) float;

// d_out layout (floats)
#define OFF_A    0
#define OFF_SC   (B_*N_*KSLOT)
#define OFF_MU   (OFF_SC + B_*KSLOT*C_)
#define OFF_SIG  (OFF_MU + B_*KSLOT*3)
#define OFF_LOSS (OFF_SIG + B_*KSLOT*9)

// workspace float layout
#define WS_MOM    0
#define WS_INVMAX (WS_MOM + B_*KSLOT*16)
#define WS_OCCTB  (WS_INVMAX + B_*KSLOT)
#define WS_OCCT   (WS_OCCTB + 256)
#define WS_ENTB   (WS_OCCT + 4)
#define WS_MSB    (WS_ENTB + 256)
#define WS_OCCLB  (WS_MSB + 256)
#define WS_REPB   (WS_OCCLB + 256)
#define WS_BS     (WS_REPB + 256)
#define WS_FEND   (WS_BS + 704)

// workspace ushort (bf16) layout
#define US_BASE  (WS_FEND*2)
#define US_SBF   US_BASE                      // s_bf16   [B*N][C]
#define US_STF   (US_SBF + B_*N_*C_)          // sT_bf16  [B][C][N]
#define US_WSL   (US_STF + B_*C_*N_)          // Wsl_bf16 [704 padded rows][C]
#define US_FT    (US_WSL + 704*C_)            // Ft_bf16  [B][16][N]
#define US_ATB   (US_FT + B_*16*N_)           // At_bf16  [B][768 padded k][N]
#define US_END   (US_ATB + (size_t)B_*768*N_)

// ---------------- helpers ----------------

__device__ __forceinline__ ushort f2bf(float x) {
  union { float f; unsigned u; } v; v.f = x;
  unsigned r = v.u + 0x7fffu + ((v.u >> 16) & 1u);
  return (ushort)(r >> 16);
}

__device__ __forceinline__ float bf2f(ushort x) {
  union { unsigned u; float f; } v; v.u = ((unsigned)x) << 16;
  return v.f;
}

__device__ __forceinline__ float blockSum256(float v, float* red) {
#pragma unroll
  for (int off = 32; off; off >>= 1) v += __shfl_xor(v, off);
  __syncthreads();
  if ((threadIdx.x & 63) == 0) red[threadIdx.x >> 6] = v;
  __syncthreads();
  return red[0] + red[1] + red[2] + red[3];
}

__device__ __forceinline__ void top4_insert(float v, float& t0, float& t1, float& t2, float& t3) {
  if (v > t3) {
    if (v > t2) {
      t3 = t2;
      if (v > t1) {
        t2 = t1;
        if (v > t0) { t1 = t0; t0 = v; } else t1 = v;
      } else t2 = v;
    } else t3 = v;
  }
}

// ---------------- fused prep, slow-branches-first dispatch order ----------------
// grid = 342 (wslots, k-tile=4) + 171 (bs) + 64 (ft) + 2048 (convert) = 2625 blocks of 256.
__global__ __launch_bounds__(256) void prep_all(const float* __restrict__ s,
                                                ushort* __restrict__ sbf,
                                                ushort* __restrict__ stf,
                                                const float* __restrict__ mu,
                                                const float* __restrict__ Sig,
                                                ushort* __restrict__ ftg,
                                                const float* __restrict__ slots,
                                                const float* __restrict__ W,
                                                ushort* __restrict__ wsl,
                                                const float* __restrict__ bvec,
                                                float* __restrict__ bs) {
  __shared__ __align__(16) char PS[16640];
  const int bid = blockIdx.x;
  const int t = threadIdx.x;
  if (bid < 342) {
    // wslots_bf16: 4 k-rows x 256 c-cols per block; 8-deep W load batching
    float (*SL)[512] = (float(*)[512])PS;
    const int idx = bid;
    const int k0 = (idx % 171) * 4;
    const int c = (idx / 171) * 256 + t;
    for (int id2 = t; id2 < 4 * 512; id2 += 256) {
      int kk = id2 >> 9, d = id2 & 511;
      SL[kk][d] = (k0 + kk < KSLOT) ? slots[(size_t)(k0 + kk) * C_ + d] : 0.f;
    }
    __syncthreads();
    float acc[4];
#pragma unroll
    for (int i = 0; i < 4; ++i) acc[i] = 0.f;
    for (int d0 = 0; d0 < C_; d0 += 8) {
      float wv[8];
#pragma unroll
      for (int j = 0; j < 8; ++j) wv[j] = W[(size_t)(d0 + j) * C_ + c];
#pragma unroll
      for (int j = 0; j < 8; ++j) {
#pragma unroll
        for (int i = 0; i < 4; ++i) acc[i] += SL[i][d0 + j] * wv[j];
      }
    }
#pragma unroll
    for (int i = 0; i < 4; ++i)
      if (k0 + i < KSLOT) wsl[(size_t)(k0 + i) * C_ + c] = f2bf(acc[i]);
  } else if (bid < 513) {
    // bs: wave-per-k, coalesced row reads + shuffle reduce
    const int widx = (bid - 342) * 4 + (t >> 6);   // k index
    const int lane = t & 63;
    if (widx < KSLOT) {
      const float* srow = slots + (size_t)widx * C_;
      float acc = 0.f;
#pragma unroll
      for (int j = 0; j < 8; ++j) {
        int d = lane + j * 64;
        acc += srow[d] * bvec[d];
      }
#pragma unroll
      for (int off = 32; off; off >>= 1) acc += __shfl_xor(acc, off);
      if (lane == 0) bs[widx] = acc;
    }
  } else if (bid < 577) {
    // build_features_t
    ushort (*FT)[272] = (ushort(*)[272])PS;
    const int fb = bid - 513;
    const size_t ng = (size_t)fb * 256 + t;
    const float* mp = mu + ng * 3;
    const float* sp = Sig + ng * 9;
    float m0 = mp[0], m1 = mp[1], m2 = mp[2];
    FT[0][t] = 0x3F80;
    FT[1][t] = f2bf(m0); FT[2][t] = f2bf(m1); FT[3][t] = f2bf(m2);
    FT[4][t] = f2bf(m0 * m0); FT[5][t] = f2bf(m0 * m1); FT[6][t] = f2bf(m0 * m2);
    FT[7][t] = f2bf(m1 * m1); FT[8][t] = f2bf(m1 * m2); FT[9][t] = f2bf(m2 * m2);
    FT[10][t] = f2bf(sp[0]); FT[11][t] = f2bf(sp[1]); FT[12][t] = f2bf(sp[2]);
    FT[13][t] = f2bf(sp[4]); FT[14][t] = f2bf(sp[5]); FT[15][t] = f2bf(sp[8]);
    __syncthreads();
    const int b = (int)((fb * 256) >> 12);
    const int n0b = (fb * 256) & (N_ - 1);
    for (int u = t; u < 512; u += 256) {
      int f = u >> 5, off = (u & 31) * 8;
      *(uint4*)(ftg + ((size_t)b * 16 + f) * N_ + n0b + off) = *(uint4*)(&FT[f][off]);
    }
  } else {
    // convert_s: 64(n) x 64(c) tile; full-128B-line writes for both sbf and stf
    float (*T)[65] = (float(*)[65])PS;
    const int cid = bid - 577;           // 0..2047
    const int b = cid >> 9;              // 512 blocks per batch
    const int rem = cid & 511;
    const int n0 = (rem >> 3) * 64;      // 64 n-tiles
    const int c0 = (rem & 7) * 64;       // 8 c-tiles
    const int tr = t >> 4;               // 0..15
    const int tc = (t & 15) * 4;         // 0..60
#pragma unroll
    for (int i = 0; i < 4; ++i) {
      const int row = i * 16 + tr;       // 0..63
      float4 v = *(const float4*)(s + ((size_t)(b * N_ + n0 + row)) * C_ + c0 + tc);
      ushort4 u;
      u.x = f2bf(v.x); u.y = f2bf(v.y); u.z = f2bf(v.z); u.w = f2bf(v.w);
      *(ushort4*)(sbf + ((size_t)(b * N_ + n0 + row)) * C_ + c0 + tc) = u;
      T[row][tc + 0] = v.x; T[row][tc + 1] = v.y;
      T[row][tc + 2] = v.z; T[row][tc + 3] = v.w;
    }
    __syncthreads();
#pragma unroll
    for (int i = 0; i < 4; ++i) {
      const int c = i * 16 + tr;         // 0..63
      const int n4 = tc;                 // 0..60
      ushort4 o;
      o.x = f2bf(T[n4 + 0][c]); o.y = f2bf(T[n4 + 1][c]);
      o.z = f2bf(T[n4 + 2][c]); o.w = f2bf(T[n4 + 3][c]);
      *(ushort4*)(stf + ((size_t)(b * C_ + c0 + c)) * N_ + n0 + n4) = o;
    }
  }
}

// bs kernel kept for fallback path
__global__ __launch_bounds__(256) void bs_kernel(const float* __restrict__ slots,
                                                 const float* __restrict__ bvec,
                                                 float* __restrict__ bs) {
  int k = blockIdx.x * 256 + threadIdx.x;
  if (k >= KSLOT) return;
  const float* srow = slots + (size_t)k * C_;
  float acc = 0.f;
  for (int d = 0; d < C_; ++d) acc += srow[d] * bvec[d];
  bs[k] = acc;
}

// ---------------- gemm1sm epilogue for one 32-row group (bf16 Af) ----------------
__device__ __forceinline__ void g1_epilogue(
    f32x4 (&acc)[11], const int rowbase, const int t, const int lane,
    const int rowg, const int colw,
    const float* __restrict__ bs, const float* __restrict__ mask,
    float* __restrict__ Aout, ushort* __restrict__ atb,
    float* __restrict__ entb, float* __restrict__ msb,
    ushort* Af, float (&red4)[32][4], const int binid) {
  __syncthreads();
  int cols[11]; bool valid[11];
#pragma unroll
  for (int cf = 0; cf < 11; ++cf) {
    cols[cf] = colw * 176 + cf * 16 + (lane & 15);
    valid[cf] = (cols[cf] < KSLOT);
    float bv = valid[cf] ? bs[cols[cf]] : 0.f;
#pragma unroll
    for (int r = 0; r < 4; ++r) acc[cf][r] += bv;
  }
  float m4[4];
#pragma unroll
  for (int r = 0; r < 4; ++r) m4[r] = -3.0e38f;
#pragma unroll
  for (int cf = 0; cf < 11; ++cf)
    if (valid[cf]) {
#pragma unroll
      for (int r = 0; r < 4; ++r) m4[r] = fmaxf(m4[r], acc[cf][r]);
    }
#pragma unroll
  for (int off = 1; off < 16; off <<= 1) {
#pragma unroll
    for (int r = 0; r < 4; ++r) m4[r] = fmaxf(m4[r], __shfl_xor(m4[r], off));
  }
  if ((lane & 15) == 0) {
#pragma unroll
    for (int r = 0; r < 4; ++r) red4[rowg * 16 + (lane >> 4) * 4 + r][colw] = m4[r];
  }
  __syncthreads();
#pragma unroll
  for (int r = 0; r < 4; ++r) {
    int rl = rowg * 16 + (lane >> 4) * 4 + r;
    m4[r] = fmaxf(fmaxf(red4[rl][0], red4[rl][1]), fmaxf(red4[rl][2], red4[rl][3]));
  }
  __syncthreads();
  float s4[4] = {0.f, 0.f, 0.f, 0.f};
#pragma unroll
  for (int cf = 0; cf < 11; ++cf)
    if (valid[cf]) {
#pragma unroll
      for (int r = 0; r < 4; ++r) {
        float e = __expf(acc[cf][r] - m4[r]);
        acc[cf][r] = e;
        s4[r] += e;
      }
    }
#pragma unroll
  for (int off = 1; off < 16; off <<= 1) {
#pragma unroll
    for (int r = 0; r < 4; ++r) s4[r] += __shfl_xor(s4[r], off);
  }
  if ((lane & 15) == 0) {
#pragma unroll
    for (int r = 0; r < 4; ++r) red4[rowg * 16 + (lane >> 4) * 4 + r][colw] = s4[r];
  }
  __syncthreads();
  float inv4[4], mr4[4];
#pragma unroll
  for (int r = 0; r < 4; ++r) {
    int rl = rowg * 16 + (lane >> 4) * 4 + r;
    float S = red4[rl][0] + red4[rl][1] + red4[rl][2] + red4[rl][3];
    inv4[r] = 1.f / S;
    mr4[r] = mask[rowbase + rl];
  }
  __syncthreads();
  float ent4[4] = {0.f, 0.f, 0.f, 0.f};
#pragma unroll
  for (int cf = 0; cf < 11; ++cf)
    if (valid[cf]) {
#pragma unroll
      for (int r = 0; r < 4; ++r) {
        int rl = rowg * 16 + (lane >> 4) * 4 + r;
        float a = acc[cf][r] * inv4[r] * mr4[r];
        Af[rl * KSLOT + cols[cf]] = f2bf(a);
        float ac = fmaxf(a, 1e-8f);
        ent4[r] -= ac * __logf(ac);
      }
    }
#pragma unroll
  for (int off = 1; off < 16; off <<= 1) {
#pragma unroll
    for (int r = 0; r < 4; ++r) ent4[r] += __shfl_xor(ent4[r], off);
  }
  if ((lane & 15) == 0) {
#pragma unroll
    for (int r = 0; r < 4; ++r) red4[rowg * 16 + (lane >> 4) * 4 + r][colw] = ent4[r];
  }
  __syncthreads();
  if (t < 64) {
    float er = 0.f, ms = 0.f;
    if (t < 32) {
      float e = red4[t][0] + red4[t][1] + red4[t][2] + red4[t][3];
      float m = mask[rowbase + t];
      er = e * m; ms = m;
    }
#pragma unroll
    for (int off = 32; off; off >>= 1) { er += __shfl_xor(er, off); ms += __shfl_xor(ms, off); }
    if (t == 0) {
      atomicAdd(&entb[binid], er);
      atomicAdd(&msb[binid], ms);
    }
  }
  // A fp32 write from bf16 Af
  float* Ag = Aout + (size_t)rowbase * KSLOT;
  for (int i = t; i < (32 * KSLOT) / 4; i += 512) {
    ushort4 u4 = *(const ushort4*)(Af + i * 4);
    float4 v;
    v.x = bf2f(u4.x); v.y = bf2f(u4.y); v.z = bf2f(u4.z); v.w = bf2f(u4.w);
    *(float4*)(Ag + i * 4) = v;
  }
  {
    const int bb = rowbase >> 12;
    const int n0b = rowbase & (N_ - 1);
    ushort* Atb = atb + ((size_t)bb * 768) * N_ + n0b;
    for (int u = t; u < KSLOT * 4; u += 512) {
      int k = u >> 2, q = u & 3;
      ushort tmp[8];
#pragma unroll
      for (int j = 0; j < 8; ++j) tmp[j] = Af[(q * 8 + j) * KSLOT + k];
      *(uint4*)(Atb + (size_t)k * N_ + q * 8) = *(uint4*)tmp;
    }
  }
}

// ---------------- FUSED: logits + softmax + A/At writes + entropy ----------------
// 32-d slabs (16 of them), 48KB staging union'd with bf16 Af -> 2+ blocks/CU.
__global__ __launch_bounds__(512)
void gemm1sm(const ushort* __restrict__ sbf,
             const ushort* __restrict__ wsl,
             const float* __restrict__ bs,
             const float* __restrict__ mask,
             float* __restrict__ Aout,
             ushort* __restrict__ atb,
             float* __restrict__ entb,
             float* __restrict__ msb) {
  __shared__ __align__(16) char SMEM[49152];   // 768 rows x 32 bf16 = 48KB staging; Af bf16 43.7KB
  __shared__ float red4[32][4];
  const int t = threadIdx.x;
  const int lane = t & 63;
  const int w = t >> 6;
  const int rowg = w >> 2;   // 0..1
  const int colw = w & 3;    // 0..3
  const int row0 = blockIdx.x * 64;
  const int r16 = rowg * 16 + (lane & 15);

  const ushort* arow0 = sbf + (size_t)(row0 + r16) * C_ + (lane >> 4) * 8;
  const ushort* arow1 = arow0 + (size_t)32 * C_;
  bf16x8 g0 = *(const bf16x8*)(arow0);
  bf16x8 g1 = *(const bf16x8*)(arow1);
  bf16x8 p0, p1;

  f32x4 acc0[11], acc1[11];
  f32x4 zero = {0.f, 0.f, 0.f, 0.f};
#pragma unroll
  for (int cf = 0; cf < 11; ++cf) { acc0[cf] = zero; acc1[cf] = zero; }

  const int ach = (lane >> 4);
#pragma unroll
  for (int slab = 0; slab < 16; ++slab) {
    if (slab) __syncthreads();
    // stage 768 rows x 32 bf16 of wsl (rows >=704 are junk, never read by MFMA)
#pragma unroll
    for (int i = 0; i < 6; ++i) {
      int idx = t + i * 512;               // 0..3071, 16B each
      int r = idx >> 2;
      int chs = (idx & 3) ^ (r & 3);       // source-side swizzle over 4 pieces
      const ushort* g = wsl + (size_t)r * C_ + slab * 32 + chs * 8;
      char* l = (char*)SMEM + (t & 448) * 16 + i * 8192;  // wave-uniform base
      __builtin_amdgcn_global_load_lds(
          (const __attribute__((address_space(1))) void*)g,
          (__attribute__((address_space(3))) void*)l, 16, 0, 0);
    }
    __syncthreads();
    if (slab < 15) {
      p0 = *(const bf16x8*)(arow0 + (slab + 1) * 32);
      p1 = *(const bf16x8*)(arow1 + (slab + 1) * 32);
    }
#pragma unroll
    for (int cf = 0; cf < 11; ++cf) {
      int br = colw * 176 + cf * 16 + (lane & 15);
      bf16x8 bf = *(const bf16x8*)(SMEM + br * 64 + ((ach * 16) ^ ((br & 3) << 4)));
      acc0[cf] = __builtin_amdgcn_mfma_f32_16x16x32_bf16(g0, bf, acc0[cf], 0, 0, 0);
      acc1[cf] = __builtin_amdgcn_mfma_f32_16x16x32_bf16(g1, bf, acc1[cf], 0, 0, 0);
    }
    g0 = p0; g1 = p1;
  }

  ushort* Af = (ushort*)SMEM;
  g1_epilogue(acc0, row0, t, lane, rowg, colw, bs, mask, Aout, atb, entb, msb,
              Af, red4, (blockIdx.x * 2) & 255);
  g1_epilogue(acc1, row0 + 32, t, lane, rowg, colw, bs, mask, Aout, atb, entb, msb,
              Af, red4, (blockIdx.x * 2 + 1) & 255);
}

// ---------------- gemm2t: output-split only (no atomics), full-N per block ----------------
#define G2BUFB 18432   // AtL 8192 + SsL 8192 + FtL 2048
__global__ __launch_bounds__(256) void gemm2t(const ushort* __restrict__ atb,
                                              const ushort* __restrict__ stf,
                                              const ushort* __restrict__ ftg,
                                              float* __restrict__ sc,
                                              float* __restrict__ MOM) {
  __shared__ __align__(16) char LB[2 * G2BUFB];   // 36864 B -> 4 blocks/CU
  const int t = threadIdx.x;
  const int lane = t & 63;
  const int w = t >> 6;        // 0..3
  const int wm = w >> 1;       // 0..1 (k half of 64)
  const int wn = w & 1;        // 0..1 (c half of 64)
  const int fhw = blockIdx.x;                 // 0..351
  const int logical = (fhw & 7) * 44 + (fhw >> 3);
  const int kt = logical % 11;                // 0..10
  const int ct = (logical / 11) & 7;          // 0..7
  const int b  = logical / 88;                // 0..3
  const bool do_mom = (ct == 0);
  const ushort* Ab = atb + ((size_t)b * 768 + kt * 64) * N_;
  const ushort* Sb = stf + ((size_t)b * C_ + ct * 64) * N_;
  const ushort* Fb = ftg + ((size_t)b * 16) * N_;

  f32x4 zero = {0.f, 0.f, 0.f, 0.f};
  f32x4 acc[2][2];
#pragma unroll
  for (int i = 0; i < 2; ++i)
#pragma unroll
    for (int j = 0; j < 2; ++j) acc[i][j] = zero;
  f32x4 accf[2];
#pragma unroll
  for (int i = 0; i < 2; ++i) accf[i] = zero;

#define G2_STAGE(BUFI, NB)                                                   \
  {                                                                          \
    char* AtL = LB + (BUFI) * G2BUFB;                                        \
    char* SsL = AtL + 8192;                                                  \
    char* FtL = AtL + 16384;                                                 \
    _Pragma("unroll")                                                        \
    for (int i = 0; i < 2; ++i) {                                            \
      int idx = t + i * 256;                                                 \
      int r = idx >> 3;                                                      \
      int chs = (idx & 7) ^ (r & 7);                                         \
      const ushort* g = Ab + (size_t)r * N_ + (NB) + chs * 8;                \
      char* l = AtL + i * 4096 + (t & 192) * 16;                             \
      __builtin_amdgcn_global_load_lds(                                      \
          (const __attribute__((address_space(1))) void*)g,                  \
          (__attribute__((address_space(3))) void*)l, 16, 0, 0);             \
    }                                                                        \
    _Pragma("unroll")                                                        \
    for (int i = 0; i < 2; ++i) {                                            \
      int idx = t + i * 256;                                                 \
      int r = idx >> 3;                                                      \
      int chs = (idx & 7) ^ (r & 7);                                         \
      const ushort* g = Sb + (size_t)r * N_ + (NB) + chs * 8;                \
      char* l = SsL + i * 4096 + (t & 192) * 16;                             \
      __builtin_amdgcn_global_load_lds(                                      \
          (const __attribute__((address_space(1))) void*)g,                  \
          (__attribute__((address_space(3))) void*)l, 16, 0, 0);             \
    }                                                                        \
    if (do_mom && t < 128) {                                                 \
      int idx = t;                                                           \
      int r = idx >> 3;                                                      \
      int chs = (idx & 7) ^ (r & 7);                                         \
      const ushort* g = Fb + (size_t)r * N_ + (NB) + chs * 8;                \
      char* l = FtL + (t & 192) * 16;                                       \
      __builtin_amdgcn_global_load_lds(                                      \
          (const __attribute__((address_space(1))) void*)g,                  \
          (__attribute__((address_space(3))) void*)l, 16, 0, 0);             \
    }                                                                        \
  }

  G2_STAGE(0, 0)
  for (int st = 0; st < 64; ++st) {
    const int cur = st & 1;
    __syncthreads();   // drains buf[cur] loads; all waves done computing buf[cur^1]
    if (st < 63) G2_STAGE(cur ^ 1, (st + 1) * 64)
    char* AtL = LB + cur * G2BUFB;
    char* SsL = AtL + 8192;
    char* FtL = AtL + 16384;
#pragma unroll
    for (int ks2 = 0; ks2 < 2; ++ks2) {
      const int ach = ks2 * 4 + (lane >> 4);
      bf16x8 afr[2], bfr[2];
#pragma unroll
      for (int kf = 0; kf < 2; ++kf) {
        int ar = wm * 32 + kf * 16 + (lane & 15);
        afr[kf] = *(const bf16x8*)(AtL + ar * 128 + ((ach * 16) ^ ((ar & 7) << 4)));
      }
#pragma unroll
      for (int cg = 0; cg < 2; ++cg) {
        int br = wn * 32 + cg * 16 + (lane & 15);
        bfr[cg] = *(const bf16x8*)(SsL + br * 128 + ((ach * 16) ^ ((br & 7) << 4)));
      }
#pragma unroll
      for (int kf = 0; kf < 2; ++kf)
#pragma unroll
        for (int cg = 0; cg < 2; ++cg)
          acc[kf][cg] = __builtin_amdgcn_mfma_f32_16x16x32_bf16(afr[kf], bfr[cg], acc[kf][cg], 0, 0, 0);
      if (do_mom && wn == 0) {
        int fr = lane & 15;
        bf16x8 ffr = *(const bf16x8*)(FtL + fr * 128 + ((ach * 16) ^ ((fr & 7) << 4)));
#pragma unroll
        for (int kf = 0; kf < 2; ++kf)
          accf[kf] = __builtin_amdgcn_mfma_f32_16x16x32_bf16(afr[kf], ffr, accf[kf], 0, 0, 0);
      }
    }
  }
#undef G2_STAGE

#pragma unroll
  for (int kf = 0; kf < 2; ++kf) {
#pragma unroll
    for (int r = 0; r < 4; ++r) {
      int k = kt * 64 + wm * 32 + kf * 16 + (lane >> 4) * 4 + r;
      if (k >= KSLOT) continue;
      float* dst = sc + ((size_t)(b * KSLOT + k)) * C_ + ct * 64 + wn * 32;
#pragma unroll
      for (int cg = 0; cg < 2; ++cg)
        dst[cg * 16 + (lane & 15)] = acc[kf][cg][r];
    }
  }
  if (do_mom && wn == 0) {
#pragma unroll
    for (int kf = 0; kf < 2; ++kf) {
#pragma unroll
      for (int r = 0; r < 4; ++r) {
        int k = kt * 64 + wm * 32 + kf * 16 + (lane >> 4) * 4 + r;
        if (k >= KSLOT) continue;
        MOM[((size_t)b * KSLOT + k) * 16 + (lane & 15)] = accf[kf][r];
      }
    }
  }
}

// ---------------- scale s_c by invmax ----------------
__global__ __launch_bounds__(128) void scale_sc(float* __restrict__ sc,
                                                const float* __restrict__ invmax) {
  const int bk = blockIdx.x;
  const float sv = invmax[bk];
  float4* p = (float4*)(sc + (size_t)bk * C_);
  int t = threadIdx.x;
  float4 v = p[t];
  v.x *= sv; v.y *= sv; v.z *= sv; v.w *= sv;
  p[t] = v;
}

// ---------------- moments (fp32 path, fallback only) ----------------
__global__ __launch_bounds__(256) void moments_kernel(const float* __restrict__ Amat,
                                                      const float* __restrict__ mu,
                                                      const float* __restrict__ Sig,
                                                      float* __restrict__ MOM) {
  __shared__ float red[64][17];
  const int b = blockIdx.z;
  const int kx = threadIdx.x & 63;
  const int k = blockIdx.x * 64 + kx;
  const int ng = threadIdx.x >> 6;
  const int n0 = blockIdx.y * 128;
  const bool valid = (k < KSLOT);

  float acc[16];
#pragma unroll
  for (int i = 0; i < 16; ++i) acc[i] = 0.f;

  const float* Abase = Amat + (size_t)b * N_ * KSLOT + k;
  const float* mubase = mu + ((size_t)b * N_) * 3;
  const float* sgbase = Sig + ((size_t)b * N_) * 9;

  for (int j = 0; j < 32; ++j) {
    const int n = n0 + ng + j * 4;
    float a = valid ? Abase[(size_t)n * KSLOT] : 0.f;
    const float* mp = mubase + (size_t)n * 3;
    const float* sp = sgbase + (size_t)n * 9;
    float m0 = mp[0], m1 = mp[1], m2 = mp[2];
    acc[0] += a;
    acc[1] += a * m0; acc[2] += a * m1; acc[3] += a * m2;
    acc[4] += a * m0 * m0; acc[5] += a * m0 * m1; acc[6] += a * m0 * m2;
    acc[7] += a * m1 * m1; acc[8] += a * m1 * m2; acc[9] += a * m2 * m2;
    acc[10] += a * sp[0]; acc[11] += a * sp[1]; acc[12] += a * sp[2];
    acc[13] += a * sp[4]; acc[14] += a * sp[5]; acc[15] += a * sp[8];
  }

  if (ng == 0) {
#pragma unroll
    for (int i = 0; i < 16; ++i) red[kx][i] = acc[i];
  }
  __syncthreads();
  if (ng == 1) {
#pragma unroll
    for (int i = 0; i < 16; ++i) red[kx][i] += acc[i];
  }
  __syncthreads();
  if (ng == 2) {
#pragma unroll
    for (int i = 0; i < 16; ++i) red[kx][i] += acc[i];
  }
  __syncthreads();
  if (ng == 3) {
#pragma unroll
    for (int i = 0; i < 16; ++i) red[kx][i] += acc[i];
  }
  __syncthreads();
  if (ng == 0 && valid) {
    float* dst = MOM + ((size_t)b * KSLOT + k) * 16;
#pragma unroll
    for (int i = 0; i < 16; ++i) atomicAdd(&dst[i], red[kx][i]);
  }
}

// ---------------- finalize per (b,k) ----------------
__global__ __launch_bounds__(256) void finalize_bk(const float* __restrict__ MOM,
                                                   float* __restrict__ muc,
                                                   float* __restrict__ sigc,
                                                   float* __restrict__ invmax,
                                                   float* __restrict__ occtb) {
  int bk = blockIdx.x * 256 + threadIdx.x;
  if (bk >= B_ * KSLOT) return;
  int b = bk / KSLOT;
  const float* T = MOM + (size_t)bk * 16;
  float den = T[0];
  float inv_eps = 1.f / (den + 1e-8f);
  float inv_mx = 1.f / fmaxf(den, 1e-8f);
  float mc0 = T[1] * inv_eps, mc1 = T[2] * inv_eps, mc2 = T[3] * inv_eps;
  float M0 = den * inv_eps;
  float cf = 2.f - M0;
  float S00 = (T[10] + T[4]) * inv_eps - cf * mc0 * mc0;
  float S01 = (T[11] + T[5]) * inv_eps - cf * mc0 * mc1;
  float S02 = (T[12] + T[6]) * inv_eps - cf * mc0 * mc2;
  float S11 = (T[13] + T[7]) * inv_eps - cf * mc1 * mc1;
  float S12 = (T[14] + T[8]) * inv_eps - cf * mc1 * mc2;
  float S22 = (T[15] + T[9]) * inv_eps - cf * mc2 * mc2;
  muc[(size_t)bk * 3 + 0] = mc0;
  muc[(size_t)bk * 3 + 1] = mc1;
  muc[(size_t)bk * 3 + 2] = mc2;
  float* sg = sigc + (size_t)bk * 9;
  sg[0] = S00; sg[1] = S01; sg[2] = S02;
  sg[3] = S01; sg[4] = S11; sg[5] = S12;
  sg[6] = S02; sg[7] = S12; sg[8] = S22;
  invmax[bk] = inv_mx;
  atomicAdd(&occtb[b * 64 + (threadIdx.x & 63)], den);
}

// ---------------- occ loss (merged occT reduce) ----------------
__global__ __launch_bounds__(256) void occ_loss_kernel(const float* __restrict__ MOM,
                                                       const float* __restrict__ occtb,
                                                       float* __restrict__ occlb) {
  __shared__ float red[4];
  __shared__ float occT[4];
  int tid = threadIdx.x;
  {
    float v = occtb[tid];
#pragma unroll
    for (int off = 32; off; off >>= 1) v += __shfl_xor(v, off);
    if ((tid & 63) == 0) occT[tid >> 6] = v;
  }
  __syncthreads();
  int bk = blockIdx.x * 256 + tid;
  float d2 = 0.f;
  if (bk < B_ * KSLOT) {
    int b = bk / KSLOT;
    float den = MOM[(size_t)bk * 16];
    float occ = den / fmaxf(occT[b], 1e-8f);
    float d = occ - (1.f / (float)KSLOT);
    d2 = d * d;
  }
  float ssum = blockSum256(d2, red);
  if (tid == 0) occlb[blockIdx.x] = ssum;
}

// ---------------- repulsion ----------------
__global__ __launch_bounds__(256) void repulsion_kernel2(const float* __restrict__ muc,
                                                         const float* __restrict__ sigc,
                                                         float* __restrict__ repb) {
  __shared__ float L[KSLOT * 13];
  const int b = blockIdx.y;
  const int t = threadIdx.x;
  const float* mb = muc + (size_t)b * KSLOT * 3;
  const float* sb = sigc + (size_t)b * KSLOT * 9;
  for (int idx = t; idx < KSLOT * 3; idx += 256) {
    int r = idx / 3, c = idx - r * 3;
    L[r * 13 + c] = mb[idx];
  }
  for (int idx = t; idx < KSLOT * 9; idx += 256) {
    int r = idx / 9, c = idx - r * 9;
    L[r * 13 + 3 + c] = sb[idx];
  }
  __syncthreads();
  const int w = t >> 6, lane = t & 63;
  const int p = blockIdx.x * 4 + w;
  if (p >= KSLOT) return;
  const float* Lp = L + p * 13;
  const float mp0 = Lp[0], mp1 = Lp[1], mp2 = Lp[2];
  const float pa = Lp[3], pb = Lp[4], pc = Lp[5], pd = Lp[7], pe = Lp[8], pf = Lp[11];
  float t0 = -3e38f, t1 = -3e38f, t2 = -3e38f, t3 = -3e38f;
  for (int q = lane; q < KSLOT; q += 64) {
    if (q == p) continue;
    const float* Lq = L + q * 13;
    float d0 = mp0 - Lq[0];
    float d1 = mp1 - Lq[1];
    float d2 = mp2 - Lq[2];
    float a  = pa + Lq[3] + 1e-6f;
    float bb = pb + Lq[4];
    float cc = pc + Lq[5];
    float d  = pd + Lq[7] + 1e-6f;
    float e  = pe + Lq[8];
    float f  = pf + Lq[11] + 1e-6f;
    float C00 = d * f - e * e;
    float C01 = cc * e - bb * f;
    float C02 = bb * e - cc * d;
    float C11 = a * f - cc * cc;
    float C12 = bb * cc - a * e;
    float C22 = a * d - bb * bb;
    float det = a * C00 + bb * C01 + cc * C02;
    float dist2 = (C00 * d0 * d0 + C11 * d1 * d1 + C22 * d2 * d2 +
                   2.f * (C01 * d0 * d1 + C02 * d0 * d2 + C12 * d1 * d2)) / det;
    top4_insert(-0.5f * dist2, t0, t1, t2, t3);
  }
#pragma unroll
  for (int off = 1; off < 64; off <<= 1) {
    float u0 = __shfl_xor(t0, off);
    float u1 = __shfl_xor(t1, off);
    float u2 = __shfl_xor(t2, off);
    float u3 = __shfl_xor(t3, off);
    top4_insert(u0, t0, t1, t2, t3);
    top4_insert(u1, t0, t1, t2, t3);
    top4_insert(u2, t0, t1, t2, t3);
    top4_insert(u3, t0, t1, t2, t3);
  }
  if (lane == 0) {
    float s = fmaxf(t0 + 1.f, 0.f) + fmaxf(t1 + 1.f, 0.f) +
              fmaxf(t2 + 1.f, 0.f) + fmaxf(t3 + 1.f, 0.f);
    atomicAdd(&repb[(b * KSLOT + p) & 255], s);
  }
}

// ---------------- final scalars ----------------
__global__ __launch_bounds__(256) void final_scalars(const float* __restrict__ entb,
                                                     const float* __restrict__ msb,
                                                     const float* __restrict__ occlb,
                                                     const float* __restrict__ repb,
                                                     float* __restrict__ out) {
  __shared__ float red[4];
  int tid = threadIdx.x;
  float e = blockSum256(entb[tid], red);
  float ms = blockSum256(msb[tid], red);
  float oc = blockSum256(occlb[tid], red);
  float rp = blockSum256(repb[tid], red);
  if (tid == 0) {
    float loss_ent = e / fmaxf(ms, 1.f);
    float loss_occ = oc / (float)(B_ * KSLOT);
    float loss_rep = rp / (float)(B_ * KSLOT * 4);
    out[0] = loss_occ;
    out[1] = loss_rep;
    out[2] = loss_ent;
    out[3] = 1.0f * loss_occ + 0.1f * loss_rep + 0.01f * loss_ent;
  }
}

// ================= fp32 fallback (used only if ws too small) =================

__global__ __launch_bounds__(256) void wslots_kernel(const float* __restrict__ slots,
                                                     const float* __restrict__ W,
                                                     float* __restrict__ Wsl) {
  int k = blockIdx.x;
  int c = blockIdx.y * 256 + threadIdx.x;
  const float* srow = slots + (size_t)k * C_;
  float acc = 0.f;
  for (int d = 0; d < C_; d += 4) {
    acc += srow[d] * W[(size_t)d * C_ + c];
    acc += srow[d + 1] * W[(size_t)(d + 1) * C_ + c];
    acc += srow[d + 2] * W[(size_t)(d + 2) * C_ + c];
    acc += srow[d + 3] * W[(size_t)(d + 3) * C_ + c];
  }
  Wsl[(size_t)k * C_ + c] = acc;
}

__global__ __launch_bounds__(256) void softmax_rows(float* __restrict__ Amat,
                                                    const float* __restrict__ mask,
                                                    float* __restrict__ entb,
                                                    float* __restrict__ msb) {
  __shared__ float red[4];
  const int row = blockIdx.x;
  const int tid = threadIdx.x;
  float* rowp = Amat + (size_t)row * KSLOT;
  const float m = mask[row];
  const bool msk = (m < 0.5f);
  float v[3];
#pragma unroll
  for (int i = 0; i < 3; ++i) {
    int k = tid + i * 256;
    if (k < KSLOT) {
      float l = rowp[k];
      v[i] = msk ? -1e9f : l;
    } else v[i] = -3.0e38f;
  }
  float lmax = fmaxf(fmaxf(v[0], v[1]), v[2]);
#pragma unroll
  for (int off = 32; off; off >>= 1) lmax = fmaxf(lmax, __shfl_xor(lmax, off));
  __syncthreads();
  if ((tid & 63) == 0) red[tid >> 6] = lmax;
  __syncthreads();
  lmax = fmaxf(fmaxf(red[0], red[1]), fmaxf(red[2], red[3]));
  float lsum = 0.f;
#pragma unroll
  for (int i = 0; i < 3; ++i) {
    int k = tid + i * 256;
    float e = (k < KSLOT) ? expf(v[i] - lmax) : 0.f;
    v[i] = e;
    lsum += e;
  }
  lsum = blockSum256(lsum, red);
  float inv = 1.f / lsum;
  float ent = 0.f;
#pragma unroll
  for (int i = 0; i < 3; ++i) {
    int k = tid + i * 256;
    if (k < KSLOT) {
      float a = v[i] * inv * m;
      rowp[k] = a;
      float ac = fmaxf(a, 1e-8f);
      ent -= ac * logf(ac);
    }
  }
  ent = blockSum256(ent, red);
  if (tid == 0) {
    int bin = blockIdx.x & 255;
    atomicAdd(&entb[bin], ent * m);
    atomicAdd(&msb[bin], m);
  }
}

__global__ __launch_bounds__(256) void gemm_nt(const float* __restrict__ Am,
                                               const float* __restrict__ Bm,
                                               const float* __restrict__ bias,
                                               float* __restrict__ Cm,
                                               int M, int Nout, int Kd,
                                               int lda, int ldb, int ldc) {
  __shared__ float As[16][132];
  __shared__ float Bs[16][132];
  const int tid = threadIdx.x;
  const int tx = tid & 15, ty = tid >> 4;
  const int m0 = blockIdx.x * 128, n0 = blockIdx.y * 128;
  float acc[8][8];
#pragma unroll
  for (int i = 0; i < 8; ++i)
#pragma unroll
    for (int j = 0; j < 8; ++j) acc[i][j] = 0.f;
  const int r = tid >> 1, hc = (tid & 1) * 8;
  for (int k0 = 0; k0 < Kd; k0 += 16) {
    float va[8], vb[8];
    int gm = m0 + r;
    if (gm < M) {
      const float* p = Am + (size_t)gm * lda + k0 + hc;
      *(float4*)(va) = *(const float4*)(p);
      *(float4*)(va + 4) = *(const float4*)(p + 4);
    } else {
#pragma unroll
      for (int i = 0; i < 8; ++i) va[i] = 0.f;
    }
    int gn = n0 + r;
    if (gn < Nout) {
      const float* p = Bm + (size_t)gn * ldb + k0 + hc;
      *(float4*)(vb) = *(const float4*)(p);
      *(float4*)(vb + 4) = *(const float4*)(p + 4);
    } else {
#pragma unroll
      for (int i = 0; i < 8; ++i) vb[i] = 0.f;
    }
#pragma unroll
    for (int i = 0; i < 8; ++i) As[hc + i][r] = va[i];
#pragma unroll
    for (int i = 0; i < 8; ++i) Bs[hc + i][r] = vb[i];
    __syncthreads();
#pragma unroll
    for (int kk = 0; kk < 16; ++kk) {
      float a[8], bb[8];
      *(float4*)(a) = *(const float4*)&As[kk][ty * 8];
      *(float4*)(a + 4) = *(const float4*)&As[kk][ty * 8 + 4];
      *(float4*)(bb) = *(const float4*)&Bs[kk][tx * 8];
      *(float4*)(bb + 4) = *(const float4*)&Bs[kk][tx * 8 + 4];
#pragma unroll
      for (int i = 0; i < 8; ++i)
#pragma unroll
        for (int j = 0; j < 8; ++j) acc[i][j] += a[i] * bb[j];
    }
    __syncthreads();
  }
#pragma unroll
  for (int i = 0; i < 8; ++i) {
    int gm = m0 + ty * 8 + i;
    if (gm >= M) continue;
    float* crow = Cm + (size_t)gm * ldc;
#pragma unroll
    for (int j = 0; j < 8; ++j) {
      int gn = n0 + tx * 8 + j;
      if (gn < Nout) crow[gn] = acc[i][j] + bias[gn];
    }
  }
}

__global__ __launch_bounds__(256) void gemm_tn(const float* __restrict__ Aall,
                                               const float* __restrict__ Ball,
                                               const float* __restrict__ scale,
                                               float* __restrict__ Call) {
  const int b = blockIdx.z;
  const float* Am = Aall + (size_t)b * N_ * KSLOT;
  const float* Bv = Ball + (size_t)b * N_ * C_;
  float* Cm = Call + (size_t)b * KSLOT * C_;
  const float* sc = scale + (size_t)b * KSLOT;
  __shared__ float As[16][132];
  __shared__ float Bs[16][68];
  const int tid = threadIdx.x;
  const int tx = tid & 15, ty = tid >> 4;
  const int m0 = blockIdx.x * 128, n0 = blockIdx.y * 64;
  float acc[8][4];
#pragma unroll
  for (int i = 0; i < 8; ++i)
#pragma unroll
    for (int j = 0; j < 4; ++j) acc[i][j] = 0.f;
  const int rr = tid >> 4;
  const int mq = tid & 15;
  const int cq = (tid & 15) * 4;
  for (int r0 = 0; r0 < N_; r0 += 16) {
#pragma unroll
    for (int i = 0; i < 8; ++i) {
      int mm = mq + 16 * i;
      int gm = m0 + mm;
      As[rr][mm] = (gm < KSLOT) ? Am[(size_t)(r0 + rr) * KSLOT + gm] : 0.f;
    }
    *(float4*)&Bs[rr][cq] = *(const float4*)(Bv + (size_t)(r0 + rr) * C_ + n0 + cq);
    __syncthreads();
#pragma unroll
    for (int kk = 0; kk < 16; ++kk) {
      float a[8], bb[4];
      *(float4*)(a) = *(const float4*)&As[kk][ty * 8];
      *(float4*)(a + 4) = *(const float4*)&As[kk][ty * 8 + 4];
      *(float4*)(bb) = *(const float4*)&Bs[kk][tx * 4];
#pragma unroll
      for (int i = 0; i < 8; ++i)
#pragma unroll
        for (int j = 0; j < 4; ++j) acc[i][j] += a[i] * bb[j];
    }
    __syncthreads();
  }
#pragma unroll
  for (int i = 0; i < 8; ++i) {
    int gm = m0 + ty * 8 + i;
    if (gm < KSLOT) {
      float s = sc[gm];
      float4 v;
      v.x = acc[i][0] * s; v.y = acc[i][1] * s; v.z = acc[i][2] * s; v.w = acc[i][3] * s;
      *(float4*)(Cm + (size_t)gm * C_ + n0 + tx * 4) = v;
    }
  }
}

// ---------------- launch ----------------
extern "C" void kernel_launch(void* const* d_in, const int* in_sizes, int n_in,
                              void* d_out, int out_size, void* d_ws, size_t ws_size,
                              hipStream_t stream) {
  const float* s     = (const float*)d_in[0];
  const float* mu    = (const float*)d_in[1];
  const float* Sig   = (const float*)d_in[2];
  const float* mask  = (const float*)d_in[3];
  const float* W     = (const float*)d_in[4];
  const float* bvec  = (const float*)d_in[5];
  const float* slots = (const float*)d_in[6];
  float* out = (float*)d_out;
  float* ws  = (float*)d_ws;

  float* Amat = out + OFF_A;
  const bool fast = (ws_size >= (size_t)US_END * 2 + 64);

  (void)hipMemsetAsync(ws, 0, WS_FEND * sizeof(float), stream);

  if (fast) {
    ushort* usw = (ushort*)ws;
    ushort* sbf = usw + US_SBF;
    ushort* stf = usw + US_STF;
    ushort* wsl = usw + US_WSL;
    ushort* ftg = usw + US_FT;
    ushort* atb = usw + US_ATB;

    prep_all<<<dim3(2625), 256, 0, stream>>>(
        s, sbf, stf, mu, Sig, ftg, slots, W, wsl, bvec, ws + WS_BS);

    gemm1sm<<<dim3(B_ * N_ / 64), 512, 0, stream>>>(
        sbf, wsl, ws + WS_BS, mask, Amat, atb, ws + WS_ENTB, ws + WS_MSB);

    gemm2t<<<dim3(352), 256, 0, stream>>>(
        atb, stf, ftg, out + OFF_SC, ws + WS_MOM);

    finalize_bk<<<dim3((B_ * KSLOT + 255) / 256), 256, 0, stream>>>(
        ws + WS_MOM, out + OFF_MU, out + OFF_SIG, ws + WS_INVMAX, ws + WS_OCCTB);

    occ_loss_kernel<<<dim3((B_ * KSLOT + 255) / 256), 256, 0, stream>>>(
        ws + WS_MOM, ws + WS_OCCTB, ws + WS_OCCLB);

    scale_sc<<<dim3(B_ * KSLOT), 128, 0, stream>>>(out + OFF_SC, ws + WS_INVMAX);

    repulsion_kernel2<<<dim3((KSLOT + 3) / 4, B_), 256, 0, stream>>>(
        out + OFF_MU, out + OFF_SIG, ws + WS_REPB);

    final_scalars<<<dim3(1), 256, 0, stream>>>(
        ws + WS_ENTB, ws + WS_MSB, ws + WS_OCCLB, ws + WS_REPB, out + OFF_LOSS);
  } else {
    float* Wsl = out + OFF_SC;

    bs_kernel<<<dim3(3), 256, 0, stream>>>(slots, bvec, ws + WS_BS);
    wslots_kernel<<<dim3(KSLOT, 2), 256, 0, stream>>>(slots, W, Wsl);
    gemm_nt<<<dim3((B_ * N_) / 128, (KSLOT + 127) / 128), 256, 0, stream>>>(
        s, Wsl, ws + WS_BS, Amat, B_ * N_, KSLOT, C_, C_, C_, KSLOT);
    softmax_rows<<<dim3(B_ * N_), 256, 0, stream>>>(Amat, mask, ws + WS_ENTB, ws + WS_MSB);
    moments_kernel<<<dim3(11, N_ / 128, B_), 256, 0, stream>>>(
        Amat, mu, Sig, ws + WS_MOM);
    finalize_bk<<<dim3((B_ * KSLOT + 255) / 256), 256, 0, stream>>>(
        ws + WS_MOM, out + OFF_MU, out + OFF_SIG, ws + WS_INVMAX, ws + WS_OCCTB);
    occ_loss_kernel<<<dim3((B_ * KSLOT + 255) / 256), 256, 0, stream>>>(
        ws + WS_MOM, ws + WS_OCCTB, ws + WS_OCCLB);
    gemm_tn<<<dim3((KSLOT + 127) / 128, C_ / 64, B_), 256, 0, stream>>>(
        Amat, s, ws + WS_INVMAX, out + OFF_SC);
    repulsion_kernel2<<<dim3((KSLOT + 3) / 4, B_), 256, 0, stream>>>(
        out + OFF_MU, out + OFF_SIG, ws + WS_REPB);
    final_scalars<<<dim3(1), 256, 0, stream>>>(
        ws + WS_ENTB, ws + WS_MSB, ws + WS_OCCLB, ws + WS_REPB, out + OFF_LOSS);
  }
}

// Round 23
// 163.312 us; speedup vs baseline: 1.0053x; 1.0053x over previous
//
#include <hip/hip_runtime.h>
#include <math.h>

#define B_    4
#define N_    4096
#define C_    512
#define KSLOT 683

using bf16x8 = __attribute__((ext_vector_type(8))) short;
using f32x4  = __attribute__((ext_vector_type(4))) float;

// d_out layout (floats)
#define OFF_A    0
#define OFF_SC   (B_*N_*KSLOT)
#define OFF_MU   (OFF_SC + B_*KSLOT*C_)
#define OFF_SIG  (OFF_MU + B_*KSLOT*3)
#define OFF_LOSS (OFF_SIG + B_*KSLOT*9)

// workspace float layout
#define WS_MOM    0
#define WS_INVMAX (WS_MOM + B_*KSLOT*16)
#define WS_OCCTB  (WS_INVMAX + B_*KSLOT)
#define WS_OCCT   (WS_OCCTB + 256)
#define WS_ENTB   (WS_OCCT + 4)
#define WS_MSB    (WS_ENTB + 256)
#define WS_OCCLB  (WS_MSB + 256)
#define WS_REPB   (WS_OCCLB + 256)
#define WS_BS     (WS_REPB + 256)
#define WS_FEND   (WS_BS + 704)

// workspace ushort (bf16) layout
#define US_BASE  (WS_FEND*2)
#define US_SBF   US_BASE                      // s_bf16   [B*N][C]
#define US_STF   (US_SBF + B_*N_*C_)          // sT_bf16  [B][C][N]
#define US_WSL   (US_STF + B_*C_*N_)          // Wsl_bf16 [704 padded rows][C]
#define US_FT    (US_WSL + 704*C_)            // Ft_bf16  [B][16][N]
#define US_ATB   (US_FT + B_*16*N_)           // At_bf16  [B][768 padded k][N]
#define US_END   (US_ATB + (size_t)B_*768*N_)

// ---------------- helpers ----------------

__device__ __forceinline__ ushort f2bf(float x) {
  union { float f; unsigned u; } v; v.f = x;
  unsigned r = v.u + 0x7fffu + ((v.u >> 16) & 1u);
  return (ushort)(r >> 16);
}

__device__ __forceinline__ float bf2f(ushort x) {
  union { unsigned u; float f; } v; v.u = ((unsigned)x) << 16;
  return v.f;
}

__device__ __forceinline__ float blockSum256(float v, float* red) {
#pragma unroll
  for (int off = 32; off; off >>= 1) v += __shfl_xor(v, off);
  __syncthreads();
  if ((threadIdx.x & 63) == 0) red[threadIdx.x >> 6] = v;
  __syncthreads();
  return red[0] + red[1] + red[2] + red[3];
}

__device__ __forceinline__ void top4_insert(float v, float& t0, float& t1, float& t2, float& t3) {
  if (v > t3) {
    if (v > t2) {
      t3 = t2;
      if (v > t1) {
        t2 = t1;
        if (v > t0) { t1 = t0; t0 = v; } else t1 = v;
      } else t2 = v;
    } else t3 = v;
  }
}

// ---------------- fused prep, slow-branches-first dispatch order ----------------
// grid = 342 (wslots, k-tile=4) + 171 (bs) + 64 (ft) + 2048 (convert) = 2625 blocks of 256.
__global__ __launch_bounds__(256) void prep_all(const float* __restrict__ s,
                                                ushort* __restrict__ sbf,
                                                ushort* __restrict__ stf,
                                                const float* __restrict__ mu,
                                                const float* __restrict__ Sig,
                                                ushort* __restrict__ ftg,
                                                const float* __restrict__ slots,
                                                const float* __restrict__ W,
                                                ushort* __restrict__ wsl,
                                                const float* __restrict__ bvec,
                                                float* __restrict__ bs) {
  __shared__ __align__(16) char PS[16640];
  const int bid = blockIdx.x;
  const int t = threadIdx.x;
  if (bid < 342) {
    // wslots_bf16: 4 k-rows x 256 c-cols per block; 8-deep W load batching
    float (*SL)[512] = (float(*)[512])PS;
    const int idx = bid;
    const int k0 = (idx % 171) * 4;
    const int c = (idx / 171) * 256 + t;
    for (int id2 = t; id2 < 4 * 512; id2 += 256) {
      int kk = id2 >> 9, d = id2 & 511;
      SL[kk][d] = (k0 + kk < KSLOT) ? slots[(size_t)(k0 + kk) * C_ + d] : 0.f;
    }
    __syncthreads();
    float acc[4];
#pragma unroll
    for (int i = 0; i < 4; ++i) acc[i] = 0.f;
    for (int d0 = 0; d0 < C_; d0 += 8) {
      float wv[8];
#pragma unroll
      for (int j = 0; j < 8; ++j) wv[j] = W[(size_t)(d0 + j) * C_ + c];
#pragma unroll
      for (int j = 0; j < 8; ++j) {
#pragma unroll
        for (int i = 0; i < 4; ++i) acc[i] += SL[i][d0 + j] * wv[j];
      }
    }
#pragma unroll
    for (int i = 0; i < 4; ++i)
      if (k0 + i < KSLOT) wsl[(size_t)(k0 + i) * C_ + c] = f2bf(acc[i]);
  } else if (bid < 513) {
    // bs: wave-per-k, coalesced row reads + shuffle reduce
    const int widx = (bid - 342) * 4 + (t >> 6);   // k index
    const int lane = t & 63;
    if (widx < KSLOT) {
      const float* srow = slots + (size_t)widx * C_;
      float acc = 0.f;
#pragma unroll
      for (int j = 0; j < 8; ++j) {
        int d = lane + j * 64;
        acc += srow[d] * bvec[d];
      }
#pragma unroll
      for (int off = 32; off; off >>= 1) acc += __shfl_xor(acc, off);
      if (lane == 0) bs[widx] = acc;
    }
  } else if (bid < 577) {
    // build_features_t
    ushort (*FT)[272] = (ushort(*)[272])PS;
    const int fb = bid - 513;
    const size_t ng = (size_t)fb * 256 + t;
    const float* mp = mu + ng * 3;
    const float* sp = Sig + ng * 9;
    float m0 = mp[0], m1 = mp[1], m2 = mp[2];
    FT[0][t] = 0x3F80;
    FT[1][t] = f2bf(m0); FT[2][t] = f2bf(m1); FT[3][t] = f2bf(m2);
    FT[4][t] = f2bf(m0 * m0); FT[5][t] = f2bf(m0 * m1); FT[6][t] = f2bf(m0 * m2);
    FT[7][t] = f2bf(m1 * m1); FT[8][t] = f2bf(m1 * m2); FT[9][t] = f2bf(m2 * m2);
    FT[10][t] = f2bf(sp[0]); FT[11][t] = f2bf(sp[1]); FT[12][t] = f2bf(sp[2]);
    FT[13][t] = f2bf(sp[4]); FT[14][t] = f2bf(sp[5]); FT[15][t] = f2bf(sp[8]);
    __syncthreads();
    const int b = (int)((fb * 256) >> 12);
    const int n0b = (fb * 256) & (N_ - 1);
    for (int u = t; u < 512; u += 256) {
      int f = u >> 5, off = (u & 31) * 8;
      *(uint4*)(ftg + ((size_t)b * 16 + f) * N_ + n0b + off) = *(uint4*)(&FT[f][off]);
    }
  } else {
    // convert_s: 64(n) x 64(c) tile; full-128B-line writes for both sbf and stf
    float (*T)[65] = (float(*)[65])PS;
    const int cid = bid - 577;           // 0..2047
    const int b = cid >> 9;              // 512 blocks per batch
    const int rem = cid & 511;
    const int n0 = (rem >> 3) * 64;      // 64 n-tiles
    const int c0 = (rem & 7) * 64;       // 8 c-tiles
    const int tr = t >> 4;               // 0..15
    const int tc = (t & 15) * 4;         // 0..60
#pragma unroll
    for (int i = 0; i < 4; ++i) {
      const int row = i * 16 + tr;       // 0..63
      float4 v = *(const float4*)(s + ((size_t)(b * N_ + n0 + row)) * C_ + c0 + tc);
      ushort4 u;
      u.x = f2bf(v.x); u.y = f2bf(v.y); u.z = f2bf(v.z); u.w = f2bf(v.w);
      *(ushort4*)(sbf + ((size_t)(b * N_ + n0 + row)) * C_ + c0 + tc) = u;
      T[row][tc + 0] = v.x; T[row][tc + 1] = v.y;
      T[row][tc + 2] = v.z; T[row][tc + 3] = v.w;
    }
    __syncthreads();
#pragma unroll
    for (int i = 0; i < 4; ++i) {
      const int c = i * 16 + tr;         // 0..63
      const int n4 = tc;                 // 0..60
      ushort4 o;
      o.x = f2bf(T[n4 + 0][c]); o.y = f2bf(T[n4 + 1][c]);
      o.z = f2bf(T[n4 + 2][c]); o.w = f2bf(T[n4 + 3][c]);
      *(ushort4*)(stf + ((size_t)(b * C_ + c0 + c)) * N_ + n0 + n4) = o;
    }
  }
}

// bs kernel kept for fallback path
__global__ __launch_bounds__(256) void bs_kernel(const float* __restrict__ slots,
                                                 const float* __restrict__ bvec,
                                                 float* __restrict__ bs) {
  int k = blockIdx.x * 256 + threadIdx.x;
  if (k >= KSLOT) return;
  const float* srow = slots + (size_t)k * C_;
  float acc = 0.f;
  for (int d = 0; d < C_; ++d) acc += srow[d] * bvec[d];
  bs[k] = acc;
}

// ---------------- gemm1sm epilogue for one 32-row group (bf16 Af) ----------------
__device__ __forceinline__ void g1_epilogue(
    f32x4 (&acc)[11], const int rowbase, const int t, const int lane,
    const int rowg, const int colw,
    const float* __restrict__ bs, const float* __restrict__ mask,
    float* __restrict__ Aout, ushort* __restrict__ atb,
    float* __restrict__ entb, float* __restrict__ msb,
    ushort* Af, float (&red4)[32][4], const int binid, const int nthreads) {
  __syncthreads();
  int cols[11]; bool valid[11];
#pragma unroll
  for (int cf = 0; cf < 11; ++cf) {
    cols[cf] = colw * 176 + cf * 16 + (lane & 15);
    valid[cf] = (cols[cf] < KSLOT);
    float bv = valid[cf] ? bs[cols[cf]] : 0.f;
#pragma unroll
    for (int r = 0; r < 4; ++r) acc[cf][r] += bv;
  }
  float m4[4];
#pragma unroll
  for (int r = 0; r < 4; ++r) m4[r] = -3.0e38f;
#pragma unroll
  for (int cf = 0; cf < 11; ++cf)
    if (valid[cf]) {
#pragma unroll
      for (int r = 0; r < 4; ++r) m4[r] = fmaxf(m4[r], acc[cf][r]);
    }
#pragma unroll
  for (int off = 1; off < 16; off <<= 1) {
#pragma unroll
    for (int r = 0; r < 4; ++r) m4[r] = fmaxf(m4[r], __shfl_xor(m4[r], off));
  }
  if ((lane & 15) == 0) {
#pragma unroll
    for (int r = 0; r < 4; ++r) red4[rowg * 16 + (lane >> 4) * 4 + r][colw] = m4[r];
  }
  __syncthreads();
#pragma unroll
  for (int r = 0; r < 4; ++r) {
    int rl = rowg * 16 + (lane >> 4) * 4 + r;
    m4[r] = fmaxf(fmaxf(red4[rl][0], red4[rl][1]), fmaxf(red4[rl][2], red4[rl][3]));
  }
  __syncthreads();
  float s4[4] = {0.f, 0.f, 0.f, 0.f};
#pragma unroll
  for (int cf = 0; cf < 11; ++cf)
    if (valid[cf]) {
#pragma unroll
      for (int r = 0; r < 4; ++r) {
        float e = __expf(acc[cf][r] - m4[r]);
        acc[cf][r] = e;
        s4[r] += e;
      }
    }
#pragma unroll
  for (int off = 1; off < 16; off <<= 1) {
#pragma unroll
    for (int r = 0; r < 4; ++r) s4[r] += __shfl_xor(s4[r], off);
  }
  if ((lane & 15) == 0) {
#pragma unroll
    for (int r = 0; r < 4; ++r) red4[rowg * 16 + (lane >> 4) * 4 + r][colw] = s4[r];
  }
  __syncthreads();
  float inv4[4], mr4[4];
#pragma unroll
  for (int r = 0; r < 4; ++r) {
    int rl = rowg * 16 + (lane >> 4) * 4 + r;
    float S = red4[rl][0] + red4[rl][1] + red4[rl][2] + red4[rl][3];
    inv4[r] = 1.f / S;
    mr4[r] = mask[rowbase + rl];
  }
  __syncthreads();
  float ent4[4] = {0.f, 0.f, 0.f, 0.f};
#pragma unroll
  for (int cf = 0; cf < 11; ++cf)
    if (valid[cf]) {
#pragma unroll
      for (int r = 0; r < 4; ++r) {
        int rl = rowg * 16 + (lane >> 4) * 4 + r;
        float a = acc[cf][r] * inv4[r] * mr4[r];
        Af[rl * KSLOT + cols[cf]] = f2bf(a);
        float ac = fmaxf(a, 1e-8f);
        ent4[r] -= ac * __logf(ac);
      }
    }
#pragma unroll
  for (int off = 1; off < 16; off <<= 1) {
#pragma unroll
    for (int r = 0; r < 4; ++r) ent4[r] += __shfl_xor(ent4[r], off);
  }
  if ((lane & 15) == 0) {
#pragma unroll
    for (int r = 0; r < 4; ++r) red4[rowg * 16 + (lane >> 4) * 4 + r][colw] = ent4[r];
  }
  __syncthreads();
  if (t < 64) {
    float er = 0.f, ms = 0.f;
    if (t < 32) {
      float e = red4[t][0] + red4[t][1] + red4[t][2] + red4[t][3];
      float m = mask[rowbase + t];
      er = e * m; ms = m;
    }
#pragma unroll
    for (int off = 32; off; off >>= 1) { er += __shfl_xor(er, off); ms += __shfl_xor(ms, off); }
    if (t == 0) {
      atomicAdd(&entb[binid], er);
      atomicAdd(&msb[binid], ms);
    }
  }
  // A fp32 write from bf16 Af
  float* Ag = Aout + (size_t)rowbase * KSLOT;
  for (int i = t; i < (32 * KSLOT) / 4; i += nthreads) {
    ushort4 u4 = *(const ushort4*)(Af + i * 4);
    float4 v;
    v.x = bf2f(u4.x); v.y = bf2f(u4.y); v.z = bf2f(u4.z); v.w = bf2f(u4.w);
    *(float4*)(Ag + i * 4) = v;
  }
  {
    const int bb = rowbase >> 12;
    const int n0b = rowbase & (N_ - 1);
    ushort* Atb = atb + ((size_t)bb * 768) * N_ + n0b;
    for (int u = t; u < KSLOT * 4; u += nthreads) {
      int k = u >> 2, q = u & 3;
      ushort tmp[8];
#pragma unroll
      for (int j = 0; j < 8; ++j) tmp[j] = Af[(q * 8 + j) * KSLOT + k];
      *(uint4*)(Atb + (size_t)k * N_ + q * 8) = *(uint4*)tmp;
    }
  }
}

// ---------------- FUSED: logits + softmax + A/At writes + entropy ----------------
// 32 n-rows per block -> 512 blocks = 2 blocks/CU; 32-d slabs (16), 48KB staging
// union'd with bf16 Af. One epilogue per block; cross-block overlap hides it.
__global__ __launch_bounds__(512)
void gemm1sm(const ushort* __restrict__ sbf,
             const ushort* __restrict__ wsl,
             const float* __restrict__ bs,
             const float* __restrict__ mask,
             float* __restrict__ Aout,
             ushort* __restrict__ atb,
             float* __restrict__ entb,
             float* __restrict__ msb) {
  __shared__ __align__(16) char SMEM[49152];   // 768 rows x 32 bf16 = 48KB staging; Af bf16 43.7KB
  __shared__ float red4[32][4];
  const int t = threadIdx.x;
  const int lane = t & 63;
  const int w = t >> 6;
  const int rowg = w >> 2;   // 0..1 (16-row half of the 32-row tile)
  const int colw = w & 3;    // 0..3
  const int row0 = blockIdx.x * 32;
  const int r16 = rowg * 16 + (lane & 15);

  const ushort* arow = sbf + (size_t)(row0 + r16) * C_ + (lane >> 4) * 8;
  bf16x8 g0 = *(const bf16x8*)(arow);
  bf16x8 p0;

  f32x4 acc[11];
  f32x4 zero = {0.f, 0.f, 0.f, 0.f};
#pragma unroll
  for (int cf = 0; cf < 11; ++cf) acc[cf] = zero;

  const int ach = (lane >> 4);
#pragma unroll
  for (int slab = 0; slab < 16; ++slab) {
    if (slab) __syncthreads();
    // stage 768 rows x 32 bf16 of wsl (rows >=704 are junk, never read by MFMA)
#pragma unroll
    for (int i = 0; i < 6; ++i) {
      int idx = t + i * 512;               // 0..3071, 16B each
      int r = idx >> 2;
      int chs = (idx & 3) ^ (r & 3);       // source-side swizzle over 4 pieces
      const ushort* g = wsl + (size_t)r * C_ + slab * 32 + chs * 8;
      char* l = (char*)SMEM + (t & 448) * 16 + i * 8192;  // wave-uniform base
      __builtin_amdgcn_global_load_lds(
          (const __attribute__((address_space(1))) void*)g,
          (__attribute__((address_space(3))) void*)l, 16, 0, 0);
    }
    __syncthreads();
    if (slab < 15) p0 = *(const bf16x8*)(arow + (slab + 1) * 32);
#pragma unroll
    for (int cf = 0; cf < 11; ++cf) {
      int br = colw * 176 + cf * 16 + (lane & 15);
      bf16x8 bf = *(const bf16x8*)(SMEM + br * 64 + ((ach * 16) ^ ((br & 3) << 4)));
      acc[cf] = __builtin_amdgcn_mfma_f32_16x16x32_bf16(g0, bf, acc[cf], 0, 0, 0);
    }
    g0 = p0;
  }

  ushort* Af = (ushort*)SMEM;
  g1_epilogue(acc, row0, t, lane, rowg, colw, bs, mask, Aout, atb, entb, msb,
              Af, red4, blockIdx.x & 255, 512);
}

// ---------------- gemm2t: output-split only (no atomics), full-N per block ----------------
#define G2BUFB 18432   // AtL 8192 + SsL 8192 + FtL 2048
__global__ __launch_bounds__(256) void gemm2t(const ushort* __restrict__ atb,
                                              const ushort* __restrict__ stf,
                                              const ushort* __restrict__ ftg,
                                              float* __restrict__ sc,
                                              float* __restrict__ MOM) {
  __shared__ __align__(16) char LB[2 * G2BUFB];   // 36864 B -> 4 blocks/CU
  const int t = threadIdx.x;
  const int lane = t & 63;
  const int w = t >> 6;        // 0..3
  const int wm = w >> 1;       // 0..1 (k half of 64)
  const int wn = w & 1;        // 0..1 (c half of 64)
  const int fhw = blockIdx.x;                 // 0..351
  const int logical = (fhw & 7) * 44 + (fhw >> 3);
  const int kt = logical % 11;                // 0..10
  const int ct = (logical / 11) & 7;          // 0..7
  const int b  = logical / 88;                // 0..3
  const bool do_mom = (ct == 0);
  const ushort* Ab = atb + ((size_t)b * 768 + kt * 64) * N_;
  const ushort* Sb = stf + ((size_t)b * C_ + ct * 64) * N_;
  const ushort* Fb = ftg + ((size_t)b * 16) * N_;

  f32x4 zero = {0.f, 0.f, 0.f, 0.f};
  f32x4 acc[2][2];
#pragma unroll
  for (int i = 0; i < 2; ++i)
#pragma unroll
    for (int j = 0; j < 2; ++j) acc[i][j] = zero;
  f32x4 accf[2];
#pragma unroll
  for (int i = 0; i < 2; ++i) accf[i] = zero;

#define G2_STAGE(BUFI, NB)                                                   \
  {                                                                          \
    char* AtL = LB + (BUFI) * G2BUFB;                                        \
    char* SsL = AtL + 8192;                                                  \
    char* FtL = AtL + 16384;                                                 \
    _Pragma("unroll")                                                        \
    for (int i = 0; i < 2; ++i) {                                            \
      int idx = t + i * 256;                                                 \
      int r = idx >> 3;                                                      \
      int chs = (idx & 7) ^ (r & 7);                                         \
      const ushort* g = Ab + (size_t)r * N_ + (NB) + chs * 8;                \
      char* l = AtL + i * 4096 + (t & 192) * 16;                             \
      __builtin_amdgcn_global_load_lds(                                      \
          (const __attribute__((address_space(1))) void*)g,                  \
          (__attribute__((address_space(3))) void*)l, 16, 0, 0);             \
    }                                                                        \
    _Pragma("unroll")                                                        \
    for (int i = 0; i < 2; ++i) {                                            \
      int idx = t + i * 256;                                                 \
      int r = idx >> 3;                                                      \
      int chs = (idx & 7) ^ (r & 7);                                         \
      const ushort* g = Sb + (size_t)r * N_ + (NB) + chs * 8;                \
      char* l = SsL + i * 4096 + (t & 192) * 16;                             \
      __builtin_amdgcn_global_load_lds(                                      \
          (const __attribute__((address_space(1))) void*)g,                  \
          (__attribute__((address_space(3))) void*)l, 16, 0, 0);             \
    }                                                                        \
    if (do_mom && t < 128) {                                                 \
      int idx = t;                                                           \
      int r = idx >> 3;                                                      \
      int chs = (idx & 7) ^ (r & 7);                                         \
      const ushort* g = Fb + (size_t)r * N_ + (NB) + chs * 8;                \
      char* l = FtL + (t & 192) * 16;                                       \
      __builtin_amdgcn_global_load_lds(                                      \
          (const __attribute__((address_space(1))) void*)g,                  \
          (__attribute__((address_space(3))) void*)l, 16, 0, 0);             \
    }                                                                        \
  }

  G2_STAGE(0, 0)
  for (int st = 0; st < 64; ++st) {
    const int cur = st & 1;
    __syncthreads();   // drains buf[cur] loads; all waves done computing buf[cur^1]
    if (st < 63) G2_STAGE(cur ^ 1, (st + 1) * 64)
    char* AtL = LB + cur * G2BUFB;
    char* SsL = AtL + 8192;
    char* FtL = AtL + 16384;
#pragma unroll
    for (int ks2 = 0; ks2 < 2; ++ks2) {
      const int ach = ks2 * 4 + (lane >> 4);
      bf16x8 afr[2], bfr[2];
#pragma unroll
      for (int kf = 0; kf < 2; ++kf) {
        int ar = wm * 32 + kf * 16 + (lane & 15);
        afr[kf] = *(const bf16x8*)(AtL + ar * 128 + ((ach * 16) ^ ((ar & 7) << 4)));
      }
#pragma unroll
      for (int cg = 0; cg < 2; ++cg) {
        int br = wn * 32 + cg * 16 + (lane & 15);
        bfr[cg] = *(const bf16x8*)(SsL + br * 128 + ((ach * 16) ^ ((br & 7) << 4)));
      }
#pragma unroll
      for (int kf = 0; kf < 2; ++kf)
#pragma unroll
        for (int cg = 0; cg < 2; ++cg)
          acc[kf][cg] = __builtin_amdgcn_mfma_f32_16x16x32_bf16(afr[kf], bfr[cg], acc[kf][cg], 0, 0, 0);
      if (do_mom && wn == 0) {
        int fr = lane & 15;
        bf16x8 ffr = *(const bf16x8*)(FtL + fr * 128 + ((ach * 16) ^ ((fr & 7) << 4)));
#pragma unroll
        for (int kf = 0; kf < 2; ++kf)
          accf[kf] = __builtin_amdgcn_mfma_f32_16x16x32_bf16(afr[kf], ffr, accf[kf], 0, 0, 0);
      }
    }
  }
#undef G2_STAGE

#pragma unroll
  for (int kf = 0; kf < 2; ++kf) {
#pragma unroll
    for (int r = 0; r < 4; ++r) {
      int k = kt * 64 + wm * 32 + kf * 16 + (lane >> 4) * 4 + r;
      if (k >= KSLOT) continue;
      float* dst = sc + ((size_t)(b * KSLOT + k)) * C_ + ct * 64 + wn * 32;
#pragma unroll
      for (int cg = 0; cg < 2; ++cg)
        dst[cg * 16 + (lane & 15)] = acc[kf][cg][r];
    }
  }
  if (do_mom && wn == 0) {
#pragma unroll
    for (int kf = 0; kf < 2; ++kf) {
#pragma unroll
      for (int r = 0; r < 4; ++r) {
        int k = kt * 64 + wm * 32 + kf * 16 + (lane >> 4) * 4 + r;
        if (k >= KSLOT) continue;
        MOM[((size_t)b * KSLOT + k) * 16 + (lane & 15)] = accf[kf][r];
      }
    }
  }
}

// ---------------- scale s_c by invmax ----------------
__global__ __launch_bounds__(128) void scale_sc(float* __restrict__ sc,
                                                const float* __restrict__ invmax) {
  const int bk = blockIdx.x;
  const float sv = invmax[bk];
  float4* p = (float4*)(sc + (size_t)bk * C_);
  int t = threadIdx.x;
  float4 v = p[t];
  v.x *= sv; v.y *= sv; v.z *= sv; v.w *= sv;
  p[t] = v;
}

// ---------------- moments (fp32 path, fallback only) ----------------
__global__ __launch_bounds__(256) void moments_kernel(const float* __restrict__ Amat,
                                                      const float* __restrict__ mu,
                                                      const float* __restrict__ Sig,
                                                      float* __restrict__ MOM) {
  __shared__ float red[64][17];
  const int b = blockIdx.z;
  const int kx = threadIdx.x & 63;
  const int k = blockIdx.x * 64 + kx;
  const int ng = threadIdx.x >> 6;
  const int n0 = blockIdx.y * 128;
  const bool valid = (k < KSLOT);

  float acc[16];
#pragma unroll
  for (int i = 0; i < 16; ++i) acc[i] = 0.f;

  const float* Abase = Amat + (size_t)b * N_ * KSLOT + k;
  const float* mubase = mu + ((size_t)b * N_) * 3;
  const float* sgbase = Sig + ((size_t)b * N_) * 9;

  for (int j = 0; j < 32; ++j) {
    const int n = n0 + ng + j * 4;
    float a = valid ? Abase[(size_t)n * KSLOT] : 0.f;
    const float* mp = mubase + (size_t)n * 3;
    const float* sp = sgbase + (size_t)n * 9;
    float m0 = mp[0], m1 = mp[1], m2 = mp[2];
    acc[0] += a;
    acc[1] += a * m0; acc[2] += a * m1; acc[3] += a * m2;
    acc[4] += a * m0 * m0; acc[5] += a * m0 * m1; acc[6] += a * m0 * m2;
    acc[7] += a * m1 * m1; acc[8] += a * m1 * m2; acc[9] += a * m2 * m2;
    acc[10] += a * sp[0]; acc[11] += a * sp[1]; acc[12] += a * sp[2];
    acc[13] += a * sp[4]; acc[14] += a * sp[5]; acc[15] += a * sp[8];
  }

  if (ng == 0) {
#pragma unroll
    for (int i = 0; i < 16; ++i) red[kx][i] = acc[i];
  }
  __syncthreads();
  if (ng == 1) {
#pragma unroll
    for (int i = 0; i < 16; ++i) red[kx][i] += acc[i];
  }
  __syncthreads();
  if (ng == 2) {
#pragma unroll
    for (int i = 0; i < 16; ++i) red[kx][i] += acc[i];
  }
  __syncthreads();
  if (ng == 3) {
#pragma unroll
    for (int i = 0; i < 16; ++i) red[kx][i] += acc[i];
  }
  __syncthreads();
  if (ng == 0 && valid) {
    float* dst = MOM + ((size_t)b * KSLOT + k) * 16;
#pragma unroll
    for (int i = 0; i < 16; ++i) atomicAdd(&dst[i], red[kx][i]);
  }
}

// ---------------- finalize per (b,k) ----------------
__global__ __launch_bounds__(256) void finalize_bk(const float* __restrict__ MOM,
                                                   float* __restrict__ muc,
                                                   float* __restrict__ sigc,
                                                   float* __restrict__ invmax,
                                                   float* __restrict__ occtb) {
  int bk = blockIdx.x * 256 + threadIdx.x;
  if (bk >= B_ * KSLOT) return;
  int b = bk / KSLOT;
  const float* T = MOM + (size_t)bk * 16;
  float den = T[0];
  float inv_eps = 1.f / (den + 1e-8f);
  float inv_mx = 1.f / fmaxf(den, 1e-8f);
  float mc0 = T[1] * inv_eps, mc1 = T[2] * inv_eps, mc2 = T[3] * inv_eps;
  float M0 = den * inv_eps;
  float cf = 2.f - M0;
  float S00 = (T[10] + T[4]) * inv_eps - cf * mc0 * mc0;
  float S01 = (T[11] + T[5]) * inv_eps - cf * mc0 * mc1;
  float S02 = (T[12] + T[6]) * inv_eps - cf * mc0 * mc2;
  float S11 = (T[13] + T[7]) * inv_eps - cf * mc1 * mc1;
  float S12 = (T[14] + T[8]) * inv_eps - cf * mc1 * mc2;
  float S22 = (T[15] + T[9]) * inv_eps - cf * mc2 * mc2;
  muc[(size_t)bk * 3 + 0] = mc0;
  muc[(size_t)bk * 3 + 1] = mc1;
  muc[(size_t)bk * 3 + 2] = mc2;
  float* sg = sigc + (size_t)bk * 9;
  sg[0] = S00; sg[1] = S01; sg[2] = S02;
  sg[3] = S01; sg[4] = S11; sg[5] = S12;
  sg[6] = S02; sg[7] = S12; sg[8] = S22;
  invmax[bk] = inv_mx;
  atomicAdd(&occtb[b * 64 + (threadIdx.x & 63)], den);
}

// ---------------- occ loss (merged occT reduce) ----------------
__global__ __launch_bounds__(256) void occ_loss_kernel(const float* __restrict__ MOM,
                                                       const float* __restrict__ occtb,
                                                       float* __restrict__ occlb) {
  __shared__ float red[4];
  __shared__ float occT[4];
  int tid = threadIdx.x;
  {
    float v = occtb[tid];
#pragma unroll
    for (int off = 32; off; off >>= 1) v += __shfl_xor(v, off);
    if ((tid & 63) == 0) occT[tid >> 6] = v;
  }
  __syncthreads();
  int bk = blockIdx.x * 256 + tid;
  float d2 = 0.f;
  if (bk < B_ * KSLOT) {
    int b = bk / KSLOT;
    float den = MOM[(size_t)bk * 16];
    float occ = den / fmaxf(occT[b], 1e-8f);
    float d = occ - (1.f / (float)KSLOT);
    d2 = d * d;
  }
  float ssum = blockSum256(d2, red);
  if (tid == 0) occlb[blockIdx.x] = ssum;
}

// ---------------- repulsion ----------------
__global__ __launch_bounds__(256) void repulsion_kernel2(const float* __restrict__ muc,
                                                         const float* __restrict__ sigc,
                                                         float* __restrict__ repb) {
  __shared__ float L[KSLOT * 13];
  const int b = blockIdx.y;
  const int t = threadIdx.x;
  const float* mb = muc + (size_t)b * KSLOT * 3;
  const float* sb = sigc + (size_t)b * KSLOT * 9;
  for (int idx = t; idx < KSLOT * 3; idx += 256) {
    int r = idx / 3, c = idx - r * 3;
    L[r * 13 + c] = mb[idx];
  }
  for (int idx = t; idx < KSLOT * 9; idx += 256) {
    int r = idx / 9, c = idx - r * 9;
    L[r * 13 + 3 + c] = sb[idx];
  }
  __syncthreads();
  const int w = t >> 6, lane = t & 63;
  const int p = blockIdx.x * 4 + w;
  if (p >= KSLOT) return;
  const float* Lp = L + p * 13;
  const float mp0 = Lp[0], mp1 = Lp[1], mp2 = Lp[2];
  const float pa = Lp[3], pb = Lp[4], pc = Lp[5], pd = Lp[7], pe = Lp[8], pf = Lp[11];
  float t0 = -3e38f, t1 = -3e38f, t2 = -3e38f, t3 = -3e38f;
  for (int q = lane; q < KSLOT; q += 64) {
    if (q == p) continue;
    const float* Lq = L + q * 13;
    float d0 = mp0 - Lq[0];
    float d1 = mp1 - Lq[1];
    float d2 = mp2 - Lq[2];
    float a  = pa + Lq[3] + 1e-6f;
    float bb = pb + Lq[4];
    float cc = pc + Lq[5];
    float d  = pd + Lq[7] + 1e-6f;
    float e  = pe + Lq[8];
    float f  = pf + Lq[11] + 1e-6f;
    float C00 = d * f - e * e;
    float C01 = cc * e - bb * f;
    float C02 = bb * e - cc * d;
    float C11 = a * f - cc * cc;
    float C12 = bb * cc - a * e;
    float C22 = a * d - bb * bb;
    float det = a * C00 + bb * C01 + cc * C02;
    float dist2 = (C00 * d0 * d0 + C11 * d1 * d1 + C22 * d2 * d2 +
                   2.f * (C01 * d0 * d1 + C02 * d0 * d2 + C12 * d1 * d2)) / det;
    top4_insert(-0.5f * dist2, t0, t1, t2, t3);
  }
#pragma unroll
  for (int off = 1; off < 64; off <<= 1) {
    float u0 = __shfl_xor(t0, off);
    float u1 = __shfl_xor(t1, off);
    float u2 = __shfl_xor(t2, off);
    float u3 = __shfl_xor(t3, off);
    top4_insert(u0, t0, t1, t2, t3);
    top4_insert(u1, t0, t1, t2, t3);
    top4_insert(u2, t0, t1, t2, t3);
    top4_insert(u3, t0, t1, t2, t3);
  }
  if (lane == 0) {
    float s = fmaxf(t0 + 1.f, 0.f) + fmaxf(t1 + 1.f, 0.f) +
              fmaxf(t2 + 1.f, 0.f) + fmaxf(t3 + 1.f, 0.f);
    atomicAdd(&repb[(b * KSLOT + p) & 255], s);
  }
}

// ---------------- final scalars ----------------
__global__ __launch_bounds__(256) void final_scalars(const float* __restrict__ entb,
                                                     const float* __restrict__ msb,
                                                     const float* __restrict__ occlb,
                                                     const float* __restrict__ repb,
                                                     float* __restrict__ out) {
  __shared__ float red[4];
  int tid = threadIdx.x;
  float e = blockSum256(entb[tid], red);
  float ms = blockSum256(msb[tid], red);
  float oc = blockSum256(occlb[tid], red);
  float rp = blockSum256(repb[tid], red);
  if (tid == 0) {
    float loss_ent = e / fmaxf(ms, 1.f);
    float loss_occ = oc / (float)(B_ * KSLOT);
    float loss_rep = rp / (float)(B_ * KSLOT * 4);
    out[0] = loss_occ;
    out[1] = loss_rep;
    out[2] = loss_ent;
    out[3] = 1.0f * loss_occ + 0.1f * loss_rep + 0.01f * loss_ent;
  }
}

// ================= fp32 fallback (used only if ws too small) =================

__global__ __launch_bounds__(256) void wslots_kernel(const float* __restrict__ slots,
                                                     const float* __restrict__ W,
                                                     float* __restrict__ Wsl) {
  int k = blockIdx.x;
  int c = blockIdx.y * 256 + threadIdx.x;
  const float* srow = slots + (size_t)k * C_;
  float acc = 0.f;
  for (int d = 0; d < C_; d += 4) {
    acc += srow[d] * W[(size_t)d * C_ + c];
    acc += srow[d + 1] * W[(size_t)(d + 1) * C_ + c];
    acc += srow[d + 2] * W[(size_t)(d + 2) * C_ + c];
    acc += srow[d + 3] * W[(size_t)(d + 3) * C_ + c];
  }
  Wsl[(size_t)k * C_ + c] = acc;
}

__global__ __launch_bounds__(256) void softmax_rows(float* __restrict__ Amat,
                                                    const float* __restrict__ mask,
                                                    float* __restrict__ entb,
                                                    float* __restrict__ msb) {
  __shared__ float red[4];
  const int row = blockIdx.x;
  const int tid = threadIdx.x;
  float* rowp = Amat + (size_t)row * KSLOT;
  const float m = mask[row];
  const bool msk = (m < 0.5f);
  float v[3];
#pragma unroll
  for (int i = 0; i < 3; ++i) {
    int k = tid + i * 256;
    if (k < KSLOT) {
      float l = rowp[k];
      v[i] = msk ? -1e9f : l;
    } else v[i] = -3.0e38f;
  }
  float lmax = fmaxf(fmaxf(v[0], v[1]), v[2]);
#pragma unroll
  for (int off = 32; off; off >>= 1) lmax = fmaxf(lmax, __shfl_xor(lmax, off));
  __syncthreads();
  if ((tid & 63) == 0) red[tid >> 6] = lmax;
  __syncthreads();
  lmax = fmaxf(fmaxf(red[0], red[1]), fmaxf(red[2], red[3]));
  float lsum = 0.f;
#pragma unroll
  for (int i = 0; i < 3; ++i) {
    int k = tid + i * 256;
    float e = (k < KSLOT) ? expf(v[i] - lmax) : 0.f;
    v[i] = e;
    lsum += e;
  }
  lsum = blockSum256(lsum, red);
  float inv = 1.f / lsum;
  float ent = 0.f;
#pragma unroll
  for (int i = 0; i < 3; ++i) {
    int k = tid + i * 256;
    if (k < KSLOT) {
      float a = v[i] * inv * m;
      rowp[k] = a;
      float ac = fmaxf(a, 1e-8f);
      ent -= ac * logf(ac);
    }
  }
  ent = blockSum256(ent, red);
  if (tid == 0) {
    int bin = blockIdx.x & 255;
    atomicAdd(&entb[bin], ent * m);
    atomicAdd(&msb[bin], m);
  }
}

__global__ __launch_bounds__(256) void gemm_nt(const float* __restrict__ Am,
                                               const float* __restrict__ Bm,
                                               const float* __restrict__ bias,
                                               float* __restrict__ Cm,
                                               int M, int Nout, int Kd,
                                               int lda, int ldb, int ldc) {
  __shared__ float As[16][132];
  __shared__ float Bs[16][132];
  const int tid = threadIdx.x;
  const int tx = tid & 15, ty = tid >> 4;
  const int m0 = blockIdx.x * 128, n0 = blockIdx.y * 128;
  float acc[8][8];
#pragma unroll
  for (int i = 0; i < 8; ++i)
#pragma unroll
    for (int j = 0; j < 8; ++j) acc[i][j] = 0.f;
  const int r = tid >> 1, hc = (tid & 1) * 8;
  for (int k0 = 0; k0 < Kd; k0 += 16) {
    float va[8], vb[8];
    int gm = m0 + r;
    if (gm < M) {
      const float* p = Am + (size_t)gm * lda + k0 + hc;
      *(float4*)(va) = *(const float4*)(p);
      *(float4*)(va + 4) = *(const float4*)(p + 4);
    } else {
#pragma unroll
      for (int i = 0; i < 8; ++i) va[i] = 0.f;
    }
    int gn = n0 + r;
    if (gn < Nout) {
      const float* p = Bm + (size_t)gn * ldb + k0 + hc;
      *(float4*)(vb) = *(const float4*)(p);
      *(float4*)(vb + 4) = *(const float4*)(p + 4);
    } else {
#pragma unroll
      for (int i = 0; i < 8; ++i) vb[i] = 0.f;
    }
#pragma unroll
    for (int i = 0; i < 8; ++i) As[hc + i][r] = va[i];
#pragma unroll
    for (int i = 0; i < 8; ++i) Bs[hc + i][r] = vb[i];
    __syncthreads();
#pragma unroll
    for (int kk = 0; kk < 16; ++kk) {
      float a[8], bb[8];
      *(float4*)(a) = *(const float4*)&As[kk][ty * 8];
      *(float4*)(a + 4) = *(const float4*)&As[kk][ty * 8 + 4];
      *(float4*)(bb) = *(const float4*)&Bs[kk][tx * 8];
      *(float4*)(bb + 4) = *(const float4*)&Bs[kk][tx * 8 + 4];
#pragma unroll
      for (int i = 0; i < 8; ++i)
#pragma unroll
        for (int j = 0; j < 8; ++j) acc[i][j] += a[i] * bb[j];
    }
    __syncthreads();
  }
#pragma unroll
  for (int i = 0; i < 8; ++i) {
    int gm = m0 + ty * 8 + i;
    if (gm >= M) continue;
    float* crow = Cm + (size_t)gm * ldc;
#pragma unroll
    for (int j = 0; j < 8; ++j) {
      int gn = n0 + tx * 8 + j;
      if (gn < Nout) crow[gn] = acc[i][j] + bias[gn];
    }
  }
}

__global__ __launch_bounds__(256) void gemm_tn(const float* __restrict__ Aall,
                                               const float* __restrict__ Ball,
                                               const float* __restrict__ scale,
                                               float* __restrict__ Call) {
  const int b = blockIdx.z;
  const float* Am = Aall + (size_t)b * N_ * KSLOT;
  const float* Bv = Ball + (size_t)b * N_ * C_;
  float* Cm = Call + (size_t)b * KSLOT * C_;
  const float* sc = scale + (size_t)b * KSLOT;
  __shared__ float As[16][132];
  __shared__ float Bs[16][68];
  const int tid = threadIdx.x;
  const int tx = tid & 15, ty = tid >> 4;
  const int m0 = blockIdx.x * 128, n0 = blockIdx.y * 64;
  float acc[8][4];
#pragma unroll
  for (int i = 0; i < 8; ++i)
#pragma unroll
    for (int j = 0; j < 4; ++j) acc[i][j] = 0.f;
  const int rr = tid >> 4;
  const int mq = tid & 15;
  const int cq = (tid & 15) * 4;
  for (int r0 = 0; r0 < N_; r0 += 16) {
#pragma unroll
    for (int i = 0; i < 8; ++i) {
      int mm = mq + 16 * i;
      int gm = m0 + mm;
      As[rr][mm] = (gm < KSLOT) ? Am[(size_t)(r0 + rr) * KSLOT + gm] : 0.f;
    }
    *(float4*)&Bs[rr][cq] = *(const float4*)(Bv + (size_t)(r0 + rr) * C_ + n0 + cq);
    __syncthreads();
#pragma unroll
    for (int kk = 0; kk < 16; ++kk) {
      float a[8], bb[4];
      *(float4*)(a) = *(const float4*)&As[kk][ty * 8];
      *(float4*)(a + 4) = *(const float4*)&As[kk][ty * 8 + 4];
      *(float4*)(bb) = *(const float4*)&Bs[kk][tx * 4];
#pragma unroll
      for (int i = 0; i < 8; ++i)
#pragma unroll
        for (int j = 0; j < 4; ++j) acc[i][j] += a[i] * bb[j];
    }
    __syncthreads();
  }
#pragma unroll
  for (int i = 0; i < 8; ++i) {
    int gm = m0 + ty * 8 + i;
    if (gm < KSLOT) {
      float s = sc[gm];
      float4 v;
      v.x = acc[i][0] * s; v.y = acc[i][1] * s; v.z = acc[i][2] * s; v.w = acc[i][3] * s;
      *(float4*)(Cm + (size_t)gm * C_ + n0 + tx * 4) = v;
    }
  }
}

// ---------------- launch ----------------
extern "C" void kernel_launch(void* const* d_in, const int* in_sizes, int n_in,
                              void* d_out, int out_size, void* d_ws, size_t ws_size,
                              hipStream_t stream) {
  const float* s     = (const float*)d_in[0];
  const float* mu    = (const float*)d_in[1];
  const float* Sig   = (const float*)d_in[2];
  const float* mask  = (const float*)d_in[3];
  const float* W     = (const float*)d_in[4];
  const float* bvec  = (const float*)d_in[5];
  const float* slots = (const float*)d_in[6];
  float* out = (float*)d_out;
  float* ws  = (float*)d_ws;

  float* Amat = out + OFF_A;
  const bool fast = (ws_size >= (size_t)US_END * 2 + 64);

  (void)hipMemsetAsync(ws, 0, WS_FEND * sizeof(float), stream);

  if (fast) {
    ushort* usw = (ushort*)ws;
    ushort* sbf = usw + US_SBF;
    ushort* stf = usw + US_STF;
    ushort* wsl = usw + US_WSL;
    ushort* ftg = usw + US_FT;
    ushort* atb = usw + US_ATB;

    prep_all<<<dim3(2625), 256, 0, stream>>>(
        s, sbf, stf, mu, Sig, ftg, slots, W, wsl, bvec, ws + WS_BS);

    gemm1sm<<<dim3(B_ * N_ / 32), 512, 0, stream>>>(
        sbf, wsl, ws + WS_BS, mask, Amat, atb, ws + WS_ENTB, ws + WS_MSB);

    gemm2t<<<dim3(352), 256, 0, stream>>>(
        atb, stf, ftg, out + OFF_SC, ws + WS_MOM);

    finalize_bk<<<dim3((B_ * KSLOT + 255) / 256), 256, 0, stream>>>(
        ws + WS_MOM, out + OFF_MU, out + OFF_SIG, ws + WS_INVMAX, ws + WS_OCCTB);

    occ_loss_kernel<<<dim3((B_ * KSLOT + 255) / 256), 256, 0, stream>>>(
        ws + WS_MOM, ws + WS_OCCTB, ws + WS_OCCLB);

    scale_sc<<<dim3(B_ * KSLOT), 128, 0, stream>>>(out + OFF_SC, ws + WS_INVMAX);

    repulsion_kernel2<<<dim3((KSLOT + 3) / 4, B_), 256, 0, stream>>>(
        out + OFF_MU, out + OFF_SIG, ws + WS_REPB);

    final_scalars<<<dim3(1), 256, 0, stream>>>(
        ws + WS_ENTB, ws + WS_MSB, ws + WS_OCCLB, ws + WS_REPB, out + OFF_LOSS);
  } else {
    float* Wsl = out + OFF_SC;

    bs_kernel<<<dim3(3), 256, 0, stream>>>(slots, bvec, ws + WS_BS);
    wslots_kernel<<<dim3(KSLOT, 2), 256, 0, stream>>>(slots, W, Wsl);
    gemm_nt<<<dim3((B_ * N_) / 128, (KSLOT + 127) / 128), 256, 0, stream>>>(
        s, Wsl, ws + WS_BS, Amat, B_ * N_, KSLOT, C_, C_, C_, KSLOT);
    softmax_rows<<<dim3(B_ * N_), 256, 0, stream>>>(Amat, mask, ws + WS_ENTB, ws + WS_MSB);
    moments_kernel<<<dim3(11, N_ / 128, B_), 256, 0, stream>>>(
        Amat, mu, Sig, ws + WS_MOM);
    finalize_bk<<<dim3((B_ * KSLOT + 255) / 256), 256, 0, stream>>>(
        ws + WS_MOM, out + OFF_MU, out + OFF_SIG, ws + WS_INVMAX, ws + WS_OCCTB);
    occ_loss_kernel<<<dim3((B_ * KSLOT + 255) / 256), 256, 0, stream>>>(
        ws + WS_MOM, ws + WS_OCCTB, ws + WS_OCCLB);
    gemm_tn<<<dim3((KSLOT + 127) / 128, C_ / 64, B_), 256, 0, stream>>>(
        Amat, s, ws + WS_INVMAX, out + OFF_SC);
    repulsion_kernel2<<<dim3((KSLOT + 3) / 4, B_), 256, 0, stream>>>(
        out + OFF_MU, out + OFF_SIG, ws + WS_REPB);
    final_scalars<<<dim3(1), 256, 0, stream>>>(
        ws + WS_ENTB, ws + WS_MSB, ws + WS_OCCLB, ws + WS_REPB, out + OFF_LOSS);
  }
}